// Round 1
// baseline (233.483 us; speedup 1.0000x reference)
//
#include <hip/hip_runtime.h>
#include <hip/hip_bf16.h>

#define B_ 4
#define S_ 2048
#define D_ 1024
#define MTOT (B_ * S_)

typedef __attribute__((ext_vector_type(8))) short bf16x8;
typedef __attribute__((ext_vector_type(4))) float f32x4;

__device__ __forceinline__ unsigned short f2bf(float f) {
  union { float f; unsigned int u; } v; v.f = f;
  unsigned int r = v.u + 0x7FFFu + ((v.u >> 16) & 1u);
  return (unsigned short)(r >> 16);
}

// ---------------- fp32 -> bf16 convert (vectorized) ----------------
__global__ void cvt_f32_bf16(const float* __restrict__ in, unsigned short* __restrict__ outp, int n4) {
  int i = blockIdx.x * blockDim.x + threadIdx.x;
  if (i >= n4) return;
  float4 v = ((const float4*)in)[i];
  ushort4 o;
  o.x = f2bf(v.x); o.y = f2bf(v.y); o.z = f2bf(v.z); o.w = f2bf(v.w);
  ((ushort4*)outp)[i] = o;
}

// ---------------- row L2-normalize fp32 -> bf16, D=1024, 256 thr/row ----------------
__global__ __launch_bounds__(256) void rownorm_f32_bf16(const float* __restrict__ in,
                                                        unsigned short* __restrict__ outp) {
  int row = blockIdx.x;
  int t = threadIdx.x;
  const float4* ip = (const float4*)(in + (long)row * D_);
  float4 v = ip[t];
  float ss = v.x * v.x + v.y * v.y + v.z * v.z + v.w * v.w;
#pragma unroll
  for (int o = 1; o < 64; o <<= 1) ss += __shfl_xor(ss, o);
  __shared__ float wsum[4];
  if ((t & 63) == 0) wsum[t >> 6] = ss;
  __syncthreads();
  float rn = rsqrtf(wsum[0] + wsum[1] + wsum[2] + wsum[3]);
  ushort4 o;
  o.x = f2bf(v.x * rn); o.y = f2bf(v.y * rn); o.z = f2bf(v.z * rn); o.w = f2bf(v.w * rn);
  ((ushort4*)(outp + (long)row * D_))[t] = o;
}

// ---------------- bf16 transpose per batch: [S][D] -> [D][S] ----------------
__global__ void transpose_bf16(const unsigned short* __restrict__ in, unsigned short* __restrict__ outp) {
  __shared__ unsigned short tile[32][33];
  int z = blockIdx.z;
  const unsigned short* ip = in + (long)z * S_ * D_;
  unsigned short* op = outp + (long)z * S_ * D_;
  int c0 = blockIdx.x * 32, r0 = blockIdx.y * 32;
  int tx = threadIdx.x, ty = threadIdx.y;
  tile[ty][tx] = ip[(long)(r0 + ty) * D_ + (c0 + tx)];
  __syncthreads();
  op[(long)(c0 + ty) * S_ + (r0 + tx)] = tile[tx][ty];
}

// ---------------- MFMA GEMM: C[M,N] = A[M,K] @ B[N,K]^T ----------------
// 128x128 tile, BK=32, 256 threads (4 waves 2x2), each wave 64x64 (4x4 frags 16x16x32)
// EPI: 0 = fp32 out, 1 = bf16 out, 2 = bf16 out with attention mask-multiply
#define BM 128
#define BN 128
#define BK 32

#define GLDS16(g, l)                                                                   \
  __builtin_amdgcn_global_load_lds((const __attribute__((address_space(1))) void*)(g), \
                                   (__attribute__((address_space(3))) void*)(l), 16, 0, 0)

template <int EPI>
__global__ __launch_bounds__(256, 2) void gemm_bt(const unsigned short* __restrict__ A,
                                                  const unsigned short* __restrict__ B,
                                                  void* __restrict__ Cv, int N, int K,
                                                  long strideA, long strideB, long strideC,
                                                  const int* __restrict__ masks) {
  __shared__ __align__(16) short lA[BM * BK];
  __shared__ __align__(16) short lB[BN * BK];
  int z = blockIdx.z;
  const unsigned short* Ab = A + (long)z * strideA;
  const unsigned short* Bb = B + (long)z * strideB;
  int t = threadIdx.x;
  int lane = t & 63, w = t >> 6;
  int wr = w >> 1, wc = w & 1;
  int brow = blockIdx.x * BM, bcol = blockIdx.y * BN;

  f32x4 acc[4][4];
#pragma unroll
  for (int m = 0; m < 4; m++)
#pragma unroll
    for (int n = 0; n < 4; n++) acc[m][n] = (f32x4){0.f, 0.f, 0.f, 0.f};

  const unsigned short* ga = Ab + (long)(brow + (t >> 2)) * K + ((t & 3) << 3);
  const unsigned short* gb = Bb + (long)(bcol + (t >> 2)) * K + ((t & 3) << 3);
  char* lAw = (char*)lA + ((t >> 6) << 10);
  char* lBw = (char*)lB + ((t >> 6) << 10);
  int fr = lane & 15, fq = lane >> 4;
  const short* pa = &lA[(wr * 64 + fr) * BK + fq * 8];
  const short* pb = &lB[(wc * 64 + fr) * BK + fq * 8];

  for (int k0 = 0; k0 < K; k0 += BK) {
    GLDS16(ga, lAw);
    GLDS16(ga + (long)64 * K, lAw + 4096);
    GLDS16(gb, lBw);
    GLDS16(gb + (long)64 * K, lBw + 4096);
    __syncthreads();  // compiler emits vmcnt(0) drain before barrier
    bf16x8 af[4], bv[4];
#pragma unroll
    for (int m = 0; m < 4; m++) af[m] = *(const bf16x8*)(pa + m * 16 * BK);
#pragma unroll
    for (int n = 0; n < 4; n++) bv[n] = *(const bf16x8*)(pb + n * 16 * BK);
#pragma unroll
    for (int m = 0; m < 4; m++)
#pragma unroll
      for (int n = 0; n < 4; n++)
        acc[m][n] = __builtin_amdgcn_mfma_f32_16x16x32_bf16(af[m], bv[n], acc[m][n], 0, 0, 0);
    __syncthreads();
    ga += BK;
    gb += BK;
  }

  long cbase = (long)z * strideC;
#pragma unroll
  for (int m = 0; m < 4; m++) {
#pragma unroll
    for (int n = 0; n < 4; n++) {
#pragma unroll
      for (int r = 0; r < 4; r++) {
        int grow = brow + wr * 64 + m * 16 + fq * 4 + r;
        int gcol = bcol + wc * 64 + n * 16 + fr;
        float v = acc[m][n][r];
        if constexpr (EPI == 0) {
          ((float*)Cv)[cbase + (long)grow * N + gcol] = v;
        } else if constexpr (EPI == 1) {
          ((unsigned short*)Cv)[cbase + (long)grow * N + gcol] = f2bf(v);
        } else {
          // keep score where (k > q) OR key is padding (masks==0); else zero
          bool keep = (gcol > grow) || (masks[z * S_ + gcol] == 0);
          ((unsigned short*)Cv)[cbase + (long)grow * N + gcol] = keep ? f2bf(v) : (unsigned short)0;
        }
      }
    }
  }
}

extern "C" void kernel_launch(void* const* d_in, const int* in_sizes, int n_in, void* d_out,
                              int out_size, void* d_ws, size_t ws_size, hipStream_t stream) {
  (void)in_sizes; (void)n_in; (void)out_size; (void)ws_size;
  const float* X = (const float*)d_in[0];
  const int* masks = (const int*)d_in[1];
  const float* Wq = (const float*)d_in[2];
  const float* Wk = (const float*)d_in[3];
  const float* Wv = (const float*)d_in[4];
  float* out = (float*)d_out;

  char* ws = (char*)d_ws;
  unsigned short* Xb = (unsigned short*)ws;  ws += (long)MTOT * D_ * 2;
  unsigned short* Wqb = (unsigned short*)ws; ws += (long)D_ * D_ * 2;
  unsigned short* Wkb = (unsigned short*)ws; ws += (long)D_ * D_ * 2;
  unsigned short* Wvb = (unsigned short*)ws; ws += (long)D_ * D_ * 2;
  float* Qf = (float*)ws;                    ws += (long)MTOT * D_ * 4;
  unsigned short* Qn = (unsigned short*)ws;  ws += (long)MTOT * D_ * 2;
  unsigned short* Kn = (unsigned short*)ws;  ws += (long)MTOT * D_ * 2;
  unsigned short* Vb = (unsigned short*)ws;  ws += (long)MTOT * D_ * 2;
  unsigned short* Vt = (unsigned short*)ws;  ws += (long)MTOT * D_ * 2;
  unsigned short* Sm = (unsigned short*)ws;  ws += (long)B_ * S_ * S_ * 2;

  // fp32 -> bf16 converts
  int n4x = MTOT * D_ / 4;
  cvt_f32_bf16<<<(n4x + 255) / 256, 256, 0, stream>>>(X, Xb, n4x);
  int n4w = D_ * D_ / 4;
  cvt_f32_bf16<<<(n4w + 255) / 256, 256, 0, stream>>>(Wq, Wqb, n4w);
  cvt_f32_bf16<<<(n4w + 255) / 256, 256, 0, stream>>>(Wk, Wkb, n4w);
  cvt_f32_bf16<<<(n4w + 255) / 256, 256, 0, stream>>>(Wv, Wvb, n4w);

  dim3 blk(256);
  // Q = X @ Wq^T (fp32) -> normalize -> Qn bf16
  gemm_bt<0><<<dim3(MTOT / BM, D_ / BN, 1), blk, 0, stream>>>(Xb, Wqb, Qf, D_, D_, 0, 0, 0, nullptr);
  rownorm_f32_bf16<<<MTOT, 256, 0, stream>>>(Qf, Qn);
  // K = X @ Wk^T (fp32, reuse Qf) -> Kn bf16
  gemm_bt<0><<<dim3(MTOT / BM, D_ / BN, 1), blk, 0, stream>>>(Xb, Wkb, Qf, D_, D_, 0, 0, 0, nullptr);
  rownorm_f32_bf16<<<MTOT, 256, 0, stream>>>(Qf, Kn);
  // V = X @ Wv^T (bf16 direct) -> transpose per batch to [D][S]
  gemm_bt<1><<<dim3(MTOT / BM, D_ / BN, 1), blk, 0, stream>>>(Xb, Wvb, Vb, D_, D_, 0, 0, 0, nullptr);
  transpose_bf16<<<dim3(D_ / 32, S_ / 32, B_), dim3(32, 32), 0, stream>>>(Vb, Vt);
  // S[b] = (Qn[b] @ Kn[b]^T) * mask  (bf16)
  gemm_bt<2><<<dim3(S_ / BM, S_ / BN, B_), blk, 0, stream>>>(Qn, Kn, Sm, S_, D_,
                                                             (long)S_ * D_, (long)S_ * D_,
                                                             (long)S_ * S_, masks);
  // out[b] = S[b] @ V[b]  (A = S [S][S], B = Vt [D][S], fp32 out)
  gemm_bt<0><<<dim3(S_ / BM, D_ / BN, B_), blk, 0, stream>>>(Sm, Vt, out, D_, S_,
                                                             (long)S_ * S_, (long)D_ * S_,
                                                             (long)S_ * D_, nullptr);
}

// Round 2
// 201.161 us; speedup vs baseline: 1.1607x; 1.1607x over previous
//
#include <hip/hip_runtime.h>
#include <hip/hip_bf16.h>

#define B_ 4
#define S_ 2048
#define D_ 1024
#define MTOT (B_ * S_)

typedef __attribute__((ext_vector_type(8))) short bf16x8;
typedef __attribute__((ext_vector_type(4))) float f32x4;

__device__ __forceinline__ unsigned short f2bf(float f) {
  union { float f; unsigned int u; } v; v.f = f;
  unsigned int r = v.u + 0x7FFFu + ((v.u >> 16) & 1u);
  return (unsigned short)(r >> 16);
}
__device__ __forceinline__ float bf2f(unsigned short u) {
  union { unsigned int u; float f; } v; v.u = ((unsigned int)u) << 16;
  return v.f;
}

// ---------------- fp32 -> bf16 convert (vectorized) ----------------
__global__ void cvt_f32_bf16(const float* __restrict__ in, unsigned short* __restrict__ outp, int n4) {
  int i = blockIdx.x * blockDim.x + threadIdx.x;
  if (i >= n4) return;
  float4 v = ((const float4*)in)[i];
  ushort4 o;
  o.x = f2bf(v.x); o.y = f2bf(v.y); o.z = f2bf(v.z); o.w = f2bf(v.w);
  ((ushort4*)outp)[i] = o;
}

// -------- row L2-normalize bf16 -> bf16; QKb is [8192][2048], half 0=Q, 1=K --------
__global__ __launch_bounds__(256) void rownorm_bf16(const unsigned short* __restrict__ QKb,
                                                    unsigned short* __restrict__ Qn,
                                                    unsigned short* __restrict__ Kn) {
  int row = blockIdx.x;
  int half = blockIdx.y;
  int tid = threadIdx.x;
  ushort4 u = *(const ushort4*)(QKb + (long)row * 2048 + half * 1024 + tid * 4);
  float x0 = bf2f(u.x), x1 = bf2f(u.y), x2 = bf2f(u.z), x3 = bf2f(u.w);
  float ss = x0 * x0 + x1 * x1 + x2 * x2 + x3 * x3;
#pragma unroll
  for (int o = 1; o < 64; o <<= 1) ss += __shfl_xor(ss, o);
  __shared__ float wsum[4];
  if ((tid & 63) == 0) wsum[tid >> 6] = ss;
  __syncthreads();
  float rn = rsqrtf(wsum[0] + wsum[1] + wsum[2] + wsum[3]);
  ushort4 o;
  o.x = f2bf(x0 * rn); o.y = f2bf(x1 * rn); o.z = f2bf(x2 * rn); o.w = f2bf(x3 * rn);
  unsigned short* op = half ? Kn : Qn;
  *(ushort4*)(op + (long)row * D_ + tid * 4) = o;
}

// ---------------- MFMA GEMM: C[M,N] = A[M,K] @ B[N,K]^T ----------------
// 128x128 tile, BK=32, 256 threads (4 waves 2x2), double-buffered LDS,
// single barrier per K-step (stage t+1 issued before compute of t).
// EPI: 0 = fp32 out; 1 = bf16 out; 2 = bf16 out * attention mask;
//      3 = bf16 out scattered to per-batch [D][S] (Vt direct)
#define BM 128
#define BN 128
#define BK 32

#define GLDS16(g, l)                                                                   \
  __builtin_amdgcn_global_load_lds((const __attribute__((address_space(1))) void*)(g), \
                                   (__attribute__((address_space(3))) void*)(l), 16, 0, 0)

template <int EPI>
__global__ __launch_bounds__(256, 2) void gemm_bt(const unsigned short* __restrict__ A,
                                                  const unsigned short* __restrict__ B,
                                                  void* __restrict__ Cv, int N, int K,
                                                  long strideA, long strideB, long strideC,
                                                  const int* __restrict__ masks) {
  __shared__ __align__(16) short lA[2][BM * BK];
  __shared__ __align__(16) short lB[2][BN * BK];
  int z = blockIdx.z;
  const unsigned short* Ab = A + (long)z * strideA;
  const unsigned short* Bb = B + (long)z * strideB;
  int tid = threadIdx.x;
  int lane = tid & 63, w = tid >> 6;
  int wr = w >> 1, wc = w & 1;
  int brow = blockIdx.x * BM, bcol = blockIdx.y * BN;

  f32x4 acc[4][4];
#pragma unroll
  for (int m = 0; m < 4; m++)
#pragma unroll
    for (int n = 0; n < 4; n++) acc[m][n] = (f32x4){0.f, 0.f, 0.f, 0.f};

  const unsigned short* ga = Ab + (long)(brow + (tid >> 2)) * K + ((tid & 3) << 3);
  const unsigned short* gb = Bb + (long)(bcol + (tid >> 2)) * K + ((tid & 3) << 3);
  int fr = lane & 15, fq = lane >> 4;

#define STAGE(buf)                                          \
  do {                                                      \
    char* la = (char*)(&lA[buf][0]) + ((tid >> 6) << 10);   \
    char* lb = (char*)(&lB[buf][0]) + ((tid >> 6) << 10);   \
    GLDS16(ga, la);                                         \
    GLDS16(ga + (long)64 * K, la + 4096);                   \
    GLDS16(gb, lb);                                         \
    GLDS16(gb + (long)64 * K, lb + 4096);                   \
    ga += BK;                                               \
    gb += BK;                                               \
  } while (0)

  STAGE(0);
  __syncthreads();  // compiler emits vmcnt(0) drain before s_barrier

  int nt = K / BK;
  for (int t = 0; t < nt; ++t) {
    int cur = t & 1;
    if (t + 1 < nt) STAGE(cur ^ 1);  // in flight across the compute below
    const short* pa = &lA[cur][(wr * 64 + fr) * BK + fq * 8];
    const short* pb = &lB[cur][(wc * 64 + fr) * BK + fq * 8];
    bf16x8 af[4], bv[4];
#pragma unroll
    for (int m = 0; m < 4; m++) af[m] = *(const bf16x8*)(pa + m * 16 * BK);
#pragma unroll
    for (int n = 0; n < 4; n++) bv[n] = *(const bf16x8*)(pb + n * 16 * BK);
#pragma unroll
    for (int m = 0; m < 4; m++)
#pragma unroll
      for (int n = 0; n < 4; n++)
        acc[m][n] = __builtin_amdgcn_mfma_f32_16x16x32_bf16(af[m], bv[n], acc[m][n], 0, 0, 0);
    __syncthreads();  // drains vmcnt (stage landed) + guards buf reuse
  }
#undef STAGE

  long cbase = (long)z * strideC;
#pragma unroll
  for (int m = 0; m < 4; m++) {
#pragma unroll
    for (int n = 0; n < 4; n++) {
#pragma unroll
      for (int r = 0; r < 4; r++) {
        int grow = brow + wr * 64 + m * 16 + fq * 4 + r;
        int gcol = bcol + wc * 64 + n * 16 + fr;
        float v = acc[m][n][r];
        if constexpr (EPI == 0) {
          ((float*)Cv)[cbase + (long)grow * N + gcol] = v;
        } else if constexpr (EPI == 1) {
          ((unsigned short*)Cv)[cbase + (long)grow * N + gcol] = f2bf(v);
        } else if constexpr (EPI == 2) {
          // keep score where (k > q) OR key is padding (masks==0); else zero
          bool keep = (gcol > grow) || (masks[z * S_ + gcol] == 0);
          ((unsigned short*)Cv)[cbase + (long)grow * N + gcol] = keep ? f2bf(v) : (unsigned short)0;
        } else {
          // Vt direct: A=Wv (grow=d), B=X (gcol=b*S+s) -> Vt[b][d][s]
          int b = gcol >> 11, s = gcol & (S_ - 1);
          ((unsigned short*)Cv)[(long)b * D_ * S_ + (long)grow * S_ + s] = f2bf(v);
        }
      }
    }
  }
}

extern "C" void kernel_launch(void* const* d_in, const int* in_sizes, int n_in, void* d_out,
                              int out_size, void* d_ws, size_t ws_size, hipStream_t stream) {
  (void)in_sizes; (void)n_in; (void)out_size; (void)ws_size;
  const float* X = (const float*)d_in[0];
  const int* masks = (const int*)d_in[1];
  const float* Wq = (const float*)d_in[2];
  const float* Wk = (const float*)d_in[3];
  const float* Wv = (const float*)d_in[4];
  float* out = (float*)d_out;

  char* ws = (char*)d_ws;
  unsigned short* Xb = (unsigned short*)ws;   ws += (long)MTOT * D_ * 2;
  unsigned short* Wqkb = (unsigned short*)ws; ws += (long)2 * D_ * D_ * 2;
  unsigned short* Wvb = (unsigned short*)ws;  ws += (long)D_ * D_ * 2;
  unsigned short* QKb = (unsigned short*)ws;  ws += (long)MTOT * 2 * D_ * 2;
  unsigned short* Qn = (unsigned short*)ws;   ws += (long)MTOT * D_ * 2;
  unsigned short* Kn = (unsigned short*)ws;   ws += (long)MTOT * D_ * 2;
  unsigned short* Vt = (unsigned short*)ws;   ws += (long)MTOT * D_ * 2;
  unsigned short* Sm = (unsigned short*)ws;   ws += (long)B_ * S_ * S_ * 2;

  // fp32 -> bf16 converts (Wq,Wk into contiguous Wqkb)
  int n4x = MTOT * D_ / 4;
  cvt_f32_bf16<<<(n4x + 255) / 256, 256, 0, stream>>>(X, Xb, n4x);
  int n4w = D_ * D_ / 4;
  cvt_f32_bf16<<<(n4w + 255) / 256, 256, 0, stream>>>(Wq, Wqkb, n4w);
  cvt_f32_bf16<<<(n4w + 255) / 256, 256, 0, stream>>>(Wk, Wqkb + (long)D_ * D_, n4w);
  cvt_f32_bf16<<<(n4w + 255) / 256, 256, 0, stream>>>(Wv, Wvb, n4w);

  dim3 blk(256);
  // [Q|K] = X @ [Wq|Wk]^T  (bf16 out, M=8192, N=2048)
  gemm_bt<1><<<dim3(MTOT / BM, 2 * D_ / BN, 1), blk, 0, stream>>>(Xb, Wqkb, QKb, 2 * D_, D_,
                                                                  0, 0, 0, nullptr);
  // normalize rows of Q-half and K-half
  rownorm_bf16<<<dim3(MTOT, 2), 256, 0, stream>>>(QKb, Qn, Kn);
  // Vt[b][d][s] = sum_k Wv[d][k] X[b*S+s][k]   (M=1024, N=8192, scatter epilogue)
  gemm_bt<3><<<dim3(D_ / BM, MTOT / BN, 1), blk, 0, stream>>>(Wvb, Xb, Vt, MTOT, D_,
                                                              0, 0, 0, nullptr);
  // S[b] = (Qn[b] @ Kn[b]^T) * mask  (bf16)
  gemm_bt<2><<<dim3(S_ / BM, S_ / BN, B_), blk, 0, stream>>>(Qn, Kn, Sm, S_, D_,
                                                             (long)S_ * D_, (long)S_ * D_,
                                                             (long)S_ * S_, masks);
  // out[b] = S[b] @ V[b]  (A = Sm [S][S], B = Vt [D][S], fp32 out)
  gemm_bt<0><<<dim3(S_ / BM, D_ / BN, B_), blk, 0, stream>>>(Sm, Vt, out, D_, S_,
                                                             (long)S_ * S_, (long)D_ * S_,
                                                             (long)S_ * D_, nullptr);
}